// Round 3
// baseline (153.245 us; speedup 1.0000x reference)
//
#include <hip/hip_runtime.h>

#define NB 16        // molecules
#define NA 2048      // atoms per molecule
#define BLOCK 256
#define JPB 64       // j atoms per block
#define SPLIT 4      // i-range splits per block (BLOCK/JPB)

__global__ void zero_pot_kernel(float* out) {
    if (threadIdx.x < NB) out[threadIdx.x] = 0.0f;
}

__global__ __launch_bounds__(BLOCK) void coulomb_kernel(
    const float* __restrict__ pos,   // [NB*NA, 3]
    const float* __restrict__ q,     // [NB*NA, 1]
    float* __restrict__ out)         // [NB + NB*NA]
{
    __shared__ float sp[NA * 3];     // 24 KB: molecule positions, [atom][xyz]
    __shared__ float sq[NA];         //  8 KB: molecule charges
    __shared__ float red[BLOCK];     //  1 KB: field reduction

    const float EPS  = 1e-9f;
    const float TINY = 1e-16f;

    const int t   = threadIdx.x;
    const int blk = blockIdx.x;
    const int blocksPerMol = NA / JPB;           // 32
    const int mol   = blk / blocksPerMol;
    const int jBase = (blk % blocksPerMol) * JPB;
    const long molAtom = (long)mol * NA;

    // Stage the whole molecule into LDS (coalesced float loads).
    for (int k = t; k < NA * 3; k += BLOCK) sp[k] = pos[molAtom * 3 + k];
    for (int k = t; k < NA;     k += BLOCK) sq[k] = q[molAtom + k];
    __syncthreads();

    const int jl     = t & (JPB - 1);     // which j atom in this block
    const int sid    = t >> 6;            // which quarter of the i-range
    const int jInMol = jBase + jl;

    const float jx = sp[jInMol * 3 + 0];
    const float jy = sp[jInMol * 3 + 1];
    const float jz = sp[jInMol * 3 + 2];

    const int iBegin = sid * (NA / SPLIT);
    const int iEnd   = iBegin + (NA / SPLIT);

    float acc = 0.0f;
    for (int i = iBegin; i < iEnd; ++i) {
        // Wave-uniform LDS reads (broadcast, conflict-free).
        float dx = sp[i * 3 + 0] - jx;
        float dy = sp[i * 3 + 1] - jy;
        float dz = sp[i * 3 + 2] - jz;
        float d2 = fmaf(dx, dx, fmaf(dy, dy, fmaf(dz, dz, TINY)));
        float dist = sqrtf(d2) + EPS;
        float inv  = 1.0f / dist;           // precise division, matches jnp
        if (i != jInMol)                    // diagonal mask
            acc = fmaf(sq[i], inv, acc);
    }

    // Combine the 4 i-range partials for each j.
    red[t] = acc;
    __syncthreads();

    if (t < JPB) {
        float field = red[t] + red[t + JPB] + red[t + 2 * JPB] + red[t + 3 * JPB];
        // q_field output (offset by NB potentials)
        out[NB + molAtom + jInMol] = field;

        // potential contribution: 0.5 * q_j * field_j, reduce across 64 lanes
        float pot = 0.5f * sq[jInMol] * field;
        #pragma unroll
        for (int off = 32; off > 0; off >>= 1)
            pot += __shfl_down(pot, off, 64);
        if (t == 0) atomicAdd(&out[mol], pot);
    }
}

extern "C" void kernel_launch(void* const* d_in, const int* in_sizes, int n_in,
                              void* d_out, int out_size, void* d_ws, size_t ws_size,
                              hipStream_t stream) {
    const float* pos = (const float*)d_in[0];
    const float* q   = (const float*)d_in[1];
    float* out = (float*)d_out;

    zero_pot_kernel<<<1, 64, 0, stream>>>(out);

    const int grid = (NB * NA) / JPB;   // 512 blocks
    coulomb_kernel<<<grid, BLOCK, 0, stream>>>(pos, q, out);
}

// Round 8
// 80.666 us; speedup vs baseline: 1.8998x; 1.8998x over previous
//
#include <hip/hip_runtime.h>

#define NB 16        // molecules
#define NA 2048      // atoms per molecule
#define BLOCK 256
#define JB 32        // j atoms per block (2 per thread-lane-group)
#define JL 16        // j lanes; JT = JB/JL = 2 j per thread
#define SPLIT 16     // i-range interleave factor (= BLOCK/JL)

__global__ void zero_pot_kernel(float* out) {
    if (threadIdx.x < NB) out[threadIdx.x] = 0.0f;
}

__global__ __launch_bounds__(BLOCK) void coulomb_kernel(
    const float* __restrict__ pos,   // [NB*NA, 3]
    const float* __restrict__ q,     // [NB*NA, 1]
    float* __restrict__ out)         // [NB + NB*NA]
{
    // SoA layout: 4 x 8 KB = 32 KB + 2.1 KB reduction = 34.2 KB -> 4 blocks/CU
    __shared__ float spx[NA], spy[NA], spz[NA], sq[NA];
    __shared__ float red[SPLIT * 33];   // stride 33: conflict-free write/read

    const int t = threadIdx.x;
    const int blocksPerMol = NA / JB;            // 64
    const int mol   = blockIdx.x / blocksPerMol;
    const int jBase = (blockIdx.x % blocksPerMol) * JB;
    const long molAtom = (long)mol * NA;

    // Stage molecule into LDS (SoA).
    for (int k = t; k < NA; k += BLOCK) {
        spx[k] = pos[(molAtom + k) * 3 + 0];
        spy[k] = pos[(molAtom + k) * 3 + 1];
        spz[k] = pos[(molAtom + k) * 3 + 2];
        sq[k]  = q[molAtom + k];
    }
    __syncthreads();

    const int jl  = t & (JL - 1);    // 0..15: which j pair
    const int sid = t >> 4;          // 0..15: which i-interleave slot
    const int j1  = jBase + jl;
    const int j2  = jBase + jl + JL;

    const float j1x = spx[j1], j1y = spy[j1], j1z = spz[j1];
    const float j2x = spx[j2], j2y = spy[j2], j2z = spz[j2];

    float acc1 = 0.0f, acc2 = 0.0f;

    // i = k*SPLIT + sid: within a wave the 4 distinct sid values give 4
    // consecutive LDS addresses -> distinct banks, broadcast to 16 lanes each.
    #pragma unroll 4
    for (int k = 0; k < NA / SPLIT; ++k) {
        const int i = k * SPLIT + sid;
        const float xi = spx[i], yi = spy[i], zi = spz[i], qi = sq[i];
        {
            float dx = xi - j1x, dy = yi - j1y, dz = zi - j1z;
            float d2 = fmaf(dx, dx, fmaf(dy, dy, fmaf(dz, dz, 1e-16f)));
            float inv = __builtin_amdgcn_rsqf(d2);   // d2 >= 1e-16: finite
            float qs  = (i == j1) ? 0.0f : qi;       // diagonal mask
            acc1 = fmaf(qs, inv, acc1);
        }
        {
            float dx = xi - j2x, dy = yi - j2y, dz = zi - j2z;
            float d2 = fmaf(dx, dx, fmaf(dy, dy, fmaf(dz, dz, 1e-16f)));
            float inv = __builtin_amdgcn_rsqf(d2);
            float qs  = (i == j2) ? 0.0f : qi;
            acc2 = fmaf(qs, inv, acc2);
        }
    }

    red[sid * 33 + jl]      = acc1;
    red[sid * 33 + jl + JL] = acc2;
    __syncthreads();

    if (t < JB) {
        float field = 0.0f;
        #pragma unroll
        for (int s = 0; s < SPLIT; ++s) field += red[s * 33 + t];

        out[NB + molAtom + jBase + t] = field;          // q_field

        float pot = 0.5f * sq[jBase + t] * field;       // potential partial
        #pragma unroll
        for (int off = 16; off > 0; off >>= 1)
            pot += __shfl_down(pot, off, 32);
        if (t == 0) atomicAdd(&out[mol], pot);
    }
}

extern "C" void kernel_launch(void* const* d_in, const int* in_sizes, int n_in,
                              void* d_out, int out_size, void* d_ws, size_t ws_size,
                              hipStream_t stream) {
    const float* pos = (const float*)d_in[0];
    const float* q   = (const float*)d_in[1];
    float* out = (float*)d_out;

    zero_pot_kernel<<<1, 64, 0, stream>>>(out);

    const int grid = NB * (NA / JB);   // 1024 blocks -> 4 blocks/CU
    coulomb_kernel<<<grid, BLOCK, 0, stream>>>(pos, q, out);
}

// Round 15
// 80.049 us; speedup vs baseline: 1.9144x; 1.0077x over previous
//
#include <hip/hip_runtime.h>

#define NB 16        // molecules
#define NA 2048      // atoms per molecule
#define BLOCK 256
#define JL 8         // j lane-groups per block
#define JT 4         // j atoms per thread
#define JB (JL*JT)   // 32 j atoms per block
#define SPLIT 32     // i-interleave slots (= BLOCK/JL)
#define RSTRIDE 33   // padded reduction row stride (conflict-free)

__global__ void zero_pot_kernel(float* out) {
    if (threadIdx.x < NB) out[threadIdx.x] = 0.0f;
}

__global__ __launch_bounds__(BLOCK) void coulomb_kernel(
    const float* __restrict__ pos,   // [NB*NA, 3]
    const float* __restrict__ q,     // [NB*NA, 1]
    float* __restrict__ out)         // [NB + NB*NA]
{
    __shared__ float4 sp4[NA];              // 32 KB: {x,y,z,q} per atom
    __shared__ float red[SPLIT * RSTRIDE];  // 4.2 KB reduction scratch

    const int t = threadIdx.x;
    const int blocksPerMol = NA / JB;            // 64
    const int mol   = blockIdx.x / blocksPerMol;
    const int jBase = (blockIdx.x % blocksPerMol) * JB;
    const long molAtom = (long)mol * NA;

    // Stage molecule into LDS as AoS float4 (pos reads hit L2/L3 after first touch).
    for (int k = t; k < NA; k += BLOCK) {
        const long a = molAtom + k;
        sp4[k] = make_float4(pos[a*3+0], pos[a*3+1], pos[a*3+2], q[a]);
    }
    __syncthreads();

    const int jl  = t & (JL - 1);    // 0..7: j lane-group
    const int sid = t >> 3;          // 0..31: i-interleave slot
    const int j0  = jBase + jl;

    float4 jp[JT];
    int    jidx[JT];
    #pragma unroll
    for (int m = 0; m < JT; ++m) {
        jidx[m] = j0 + m * JL;
        jp[m]   = sp4[jidx[m]];
    }

    float acc[JT] = {0.0f, 0.0f, 0.0f, 0.0f};

    // i = k*SPLIT + sid: per wave, 8 consecutive float4 addresses (32 banks
    // hit exactly once), broadcast to 8 lanes each -> conflict-free b128 reads.
    #pragma unroll 4
    for (int k = 0; k < NA / SPLIT; ++k) {
        const int i = k * SPLIT + sid;
        const float4 p = sp4[i];
        #pragma unroll
        for (int m = 0; m < JT; ++m) {
            float dx = p.x - jp[m].x;
            float dy = p.y - jp[m].y;
            float dz = p.z - jp[m].z;
            float d2 = fmaf(dx, dx, fmaf(dy, dy, fmaf(dz, dz, 1e-16f)));
            float inv = __builtin_amdgcn_rsqf(d2);   // d2 >= 1e-16: finite
            float qs  = (i == jidx[m]) ? 0.0f : p.w; // diagonal mask
            acc[m] = fmaf(qs, inv, acc[m]);
        }
    }

    #pragma unroll
    for (int m = 0; m < JT; ++m)
        red[sid * RSTRIDE + jl + m * JL] = acc[m];
    __syncthreads();

    if (t < JB) {
        float field = 0.0f;
        #pragma unroll
        for (int s = 0; s < SPLIT; ++s) field += red[s * RSTRIDE + t];

        out[NB + molAtom + jBase + t] = field;          // q_field

        float pot = 0.5f * sp4[jBase + t].w * field;    // potential partial
        #pragma unroll
        for (int off = 16; off > 0; off >>= 1)
            pot += __shfl_down(pot, off, 32);
        if (t == 0) atomicAdd(&out[mol], pot);
    }
}

extern "C" void kernel_launch(void* const* d_in, const int* in_sizes, int n_in,
                              void* d_out, int out_size, void* d_ws, size_t ws_size,
                              hipStream_t stream) {
    const float* pos = (const float*)d_in[0];
    const float* q   = (const float*)d_in[1];
    float* out = (float*)d_out;

    zero_pot_kernel<<<1, 64, 0, stream>>>(out);

    const int grid = NB * (NA / JB);   // 1024 blocks -> 4 blocks/CU
    coulomb_kernel<<<grid, BLOCK, 0, stream>>>(pos, q, out);
}